// Round 17
// baseline (438.271 us; speedup 1.0000x reference)
//
#include <hip/hip_runtime.h>

#define HF 128
#define OUTF 16
#define NG 64
#define NSL 8              // fp8 column slices (16 cols each), pinned to XCDs
#define SLC 16             // cols per slice
#define PBSH 7             // bucket = dst >> 7 (PB = 128 nodes/bucket)
#define PBSZ 128
#define CHUNK 4096         // edges per histogram/scatter block (391 blocks)
#define STAGE 4608         // reorder LDS stage entries (avg bucket ~2046)
#define RBLK 128           // stats reduce blocks
#define BN_EPS 1e-5f

typedef unsigned short ushortT;
typedef unsigned int uintT;
typedef unsigned char ucharT;
typedef __attribute__((ext_vector_type(8))) short bf16x8;
typedef __attribute__((ext_vector_type(4))) float f32x4;
typedef __attribute__((ext_vector_type(2))) float f32x2;

__device__ __forceinline__ float bf2f(uintT u) {
    union { uintT i; float f; } c; c.i = u << 16; return c.f;
}
__device__ __forceinline__ float bf2f_hi(uintT u) {
    union { uintT i; float f; } c; c.i = u & 0xffff0000u; return c.f;
}
__device__ __forceinline__ uintT f2bf(float f) {
    union { float f; uintT i; } c; c.f = f;
    uintT u = c.i;
    return (u + 0x7fffu + ((u >> 16) & 1u)) >> 16;
}
__device__ __forceinline__ uintT pack2(float a, float b) {
    return f2bf(a) | (f2bf(b) << 16);
}

// HW OCP e4m3 conversions (gfx950)
__device__ __forceinline__ uintT fp8_enc2(float a, float b) {
    return (uintT)__builtin_amdgcn_cvt_pk_fp8_f32(a, b, 0, false) & 0xffffu;
}
__device__ __forceinline__ void fp8_acc8(float* a, uint2 v) {
    f32x2 f;
    f = __builtin_amdgcn_cvt_pk_f32_fp8((int)v.x, false); a[0] += f.x; a[1] += f.y;
    f = __builtin_amdgcn_cvt_pk_f32_fp8((int)v.x, true);  a[2] += f.x; a[3] += f.y;
    f = __builtin_amdgcn_cvt_pk_f32_fp8((int)v.y, false); a[4] += f.x; a[5] += f.y;
    f = __builtin_amdgcn_cvt_pk_f32_fp8((int)v.y, true);  a[6] += f.x; a[7] += f.y;
}
__device__ __forceinline__ void fp8_acc16(float* a, uint4 v) {
    fp8_acc8(a,     make_uint2(v.x, v.y));
    fp8_acc8(a + 8, make_uint2(v.z, v.w));
}

// ---------------- CSR build, atomic-free (global), 5 kernels ----------------

__global__ __launch_bounds__(1024) void bhist_kernel(const int* __restrict__ dst,
                                                     int* __restrict__ bhistB,
                                                     int E, int nbkt) {
    __shared__ int h[1024];
    int t = threadIdx.x, blk = blockIdx.x;
    if (t < 1024) h[t] = 0;
    __syncthreads();
    int e0 = blk * CHUNK, e1 = min(E, e0 + CHUNK);
    for (int e = e0 + t; e < e1; e += 1024) atomicAdd(&h[dst[e] >> PBSH], 1);
    __syncthreads();
    if (t < nbkt) bhistB[blk * 1024 + t] = h[t];
}

__global__ __launch_bounds__(256) void bscan_blocks_kernel(const int* __restrict__ bhistB,
                                                           int* __restrict__ lbase,
                                                           int* __restrict__ total,
                                                           int nblk, int nbkt) {
    int bkt = blockIdx.x * 4 + (threadIdx.x >> 6);
    int lane = threadIdx.x & 63;
    if (bkt >= nbkt) return;
    int run = 0;
    for (int base = 0; base < nblk; base += 64) {
        int blk = base + lane;
        int v = (blk < nblk) ? bhistB[(size_t)blk * 1024 + bkt] : 0;
        int pre = v;
        #pragma unroll
        for (int o = 1; o < 64; o <<= 1) {
            int u = __shfl_up(pre, o);
            if (lane >= o) pre += u;
        }
        if (blk < nblk) lbase[(size_t)blk * 1024 + bkt] = run + pre - v;
        run += __shfl(pre, 63);
    }
    if (lane == 0) total[bkt] = run;
}

__global__ __launch_bounds__(1024) void bscan_base_kernel(const int* __restrict__ total,
                                                          int* __restrict__ bbase, int nbkt) {
    __shared__ int sc[1024];
    int t = threadIdx.x;
    int v = (t < nbkt) ? total[t] : 0;
    sc[t] = v;
    __syncthreads();
    for (int o = 1; o < 1024; o <<= 1) {
        int add = (t >= o) ? sc[t - o] : 0;
        __syncthreads();
        sc[t] += add;
        __syncthreads();
    }
    if (t < nbkt) {
        bbase[t] = sc[t] - v;
        if (t == nbkt - 1) bbase[nbkt] = sc[t];
    }
}

__global__ __launch_bounds__(1024) void bscatter_kernel(const int* __restrict__ src,
                                                        const int* __restrict__ dst,
                                                        const int* __restrict__ bbase,
                                                        const int* __restrict__ lbase,
                                                        uintT* __restrict__ tmp,
                                                        int E, int nbkt) {
    __shared__ int cur[1024];
    int t = threadIdx.x, blk = blockIdx.x;
    if (t < nbkt) cur[t] = bbase[t] + lbase[(size_t)blk * 1024 + t];
    __syncthreads();
    int e0 = blk * CHUNK, e1 = min(E, e0 + CHUNK);
    for (int e = e0 + t; e < e1; e += 1024) {
        int d = dst[e];
        int bkt = d >> PBSH;
        int pos = atomicAdd(&cur[bkt], 1);
        tmp[pos] = ((uintT)(d & (PBSZ - 1)) << 18) | (uintT)src[e];
    }
}

__global__ __launch_bounds__(256) void breorder_kernel(const uintT* __restrict__ tmp,
                                                       const int* __restrict__ bbase,
                                                       const float* __restrict__ x,
                                                       int* __restrict__ rowptr,
                                                       int* __restrict__ csr_src,
                                                       float* __restrict__ dis,
                                                       float* __restrict__ xp,
                                                       int n, int nbkt) {
    __shared__ int lcnt[PBSZ];
    __shared__ int sc[PBSZ];
    __shared__ int lcur[PBSZ];
    __shared__ int stage[STAGE];
    int b = blockIdx.x, t = threadIdx.x;
    int n0 = b << PBSH;
    if (n0 >= n) return;
    int start = bbase[b], end = bbase[b + 1];
    int cnt = end - start;
    if (t < PBSZ) lcnt[t] = 0;
    __syncthreads();
    for (int i = t; i < cnt; i += 256) atomicAdd(&lcnt[tmp[start + i] >> 18], 1);
    __syncthreads();
    int v = (t < PBSZ) ? lcnt[t] : 0;
    if (t < PBSZ) sc[t] = v;
    __syncthreads();
    for (int o = 1; o < PBSZ; o <<= 1) {
        int add = (t < PBSZ && t >= o) ? sc[t - o] : 0;
        __syncthreads();
        if (t < PBSZ) sc[t] += add;
        __syncthreads();
    }
    if (t < PBSZ) {
        int pre = sc[t] - v;
        lcur[t] = pre;
        int node = n0 + t;
        if (node < n) {
            rowptr[node] = start + pre;
            float d = rsqrtf((float)v + 1.0f);      // +1 = self loop
            dis[node] = d;
            xp[node] = d * x[node];
        }
    }
    if (b == nbkt - 1 && t == 0) rowptr[n] = end;
    __syncthreads();
    if (cnt <= STAGE) {
        for (int i = t; i < cnt; i += 256) {
            uintT p = tmp[start + i];
            int pos = atomicAdd(&lcur[p >> 18], 1);
            stage[pos] = (int)(p & 0x3ffffu);
        }
        __syncthreads();
        for (int i = t; i < cnt; i += 256) csr_src[start + i] = stage[i];
    } else {
        for (int i = t; i < cnt; i += 256) {
            uintT p = tmp[start + i];
            int pos = atomicAdd(&lcur[p >> 18], 1);
            csr_src[start + pos] = (int)(p & 0x3ffffu);
        }
    }
}

// ---------------- layer 0: scalar gather + fused block stats ----------------

__global__ __launch_bounds__(256) void gather1_kernel(const float* __restrict__ xp,
                                                      const int* __restrict__ rowptr,
                                                      const int* __restrict__ csr_src,
                                                      const float* __restrict__ dis,
                                                      float* __restrict__ aggx,
                                                      float* __restrict__ partial1, int n) {
    int t = threadIdx.x;
    int i = blockIdx.x * 256 + t;
    float v = 0.f;
    if (i < n) {
        float acc = xp[i];                // self loop
        int e = rowptr[i + 1];
        for (int j = rowptr[i]; j < e; ++j) acc += xp[csr_src[j]];
        v = acc * dis[i];
        aggx[i] = v;
    }
    float s = v, ss = v * v;
    for (int o = 32; o > 0; o >>= 1) { s += __shfl_down(s, o); ss += __shfl_down(ss, o); }
    __shared__ float r2[2][4];
    int wv = t >> 6, ln = t & 63;
    if (ln == 0) { r2[0][wv] = s; r2[1][wv] = ss; }
    __syncthreads();
    if (t == 0) {
        partial1[blockIdx.x * 2]     = r2[0][0] + r2[0][1] + r2[0][2] + r2[0][3];
        partial1[blockIdx.x * 2 + 1] = r2[1][0] + r2[1][1] + r2[1][2] + r2[1][3];
    }
}

__global__ void coef0_kernel(const float* __restrict__ partial1, int nblk1,
                             const float* __restrict__ W0, const float* __restrict__ g,
                             const float* __restrict__ beta, float* __restrict__ coef,
                             float invn) {
    __shared__ float rs[128], rss[128];
    int t = threadIdx.x;    // 128
    float s = 0.f, ss = 0.f;
    for (int k = t; k < nblk1; k += 128) { s += partial1[2 * k]; ss += partial1[2 * k + 1]; }
    rs[t] = s; rss[t] = ss;
    __syncthreads();
    for (int o = 64; o > 0; o >>= 1) {
        if (t < o) { rs[t] += rs[t + o]; rss[t] += rss[t + o]; }
        __syncthreads();
    }
    float m = rs[0] * invn;
    float var = rss[0] * invn - m * m;
    float w = W0[t];
    float sc = g[t] * w * rsqrtf(var * w * w + BN_EPS);
    coef[t] = sc;
    coef[HF + t] = beta[t] - m * sc;
}

// ---------------- W pre-conversion (both layers, one kernel) ----------------

__global__ void wprep2_kernel(const float* __restrict__ W1, const float* __restrict__ W2,
                              ushortT* __restrict__ Wt1, ushortT* __restrict__ Wt2) {
    int i = blockIdx.x * 256 + threadIdx.x;     // 128 blocks -> 32768
    const float* W = (i < 16384) ? W1 : W2;
    ushortT* Wt = (i < 16384) ? Wt1 : Wt2;
    int ii = i & 16383;
    int k = ii >> 7, j = ii & 127;
    int byteoff = (j << 8) + ((k << 1) ^ ((j & 7) << 4));
    *(ushortT*)((char*)Wt + byteoff) = (ushortT)f2bf(W[ii]);
}

// ---------------- MFMA GEMM: C8T[slice][n][16] = fp8(dis*(act(A)@W)) ----------------
// A (mode 1) and C8 are SLICE-MAJOR: [slice][node][16 cols].
// mode 1: A = bf16 slice-major rows, relu(v*coef+shift) on load.
// mode 2: A row = relu(aggx[row]*coef+shift) built in registers (layer 1, rank-1 input).

__global__ __launch_bounds__(256) void gemm_mfma_kernel(const ushortT* __restrict__ A,
                                                        const float* __restrict__ aggx,
                                                        const ushortT* __restrict__ Wt8,
                                                        const float* __restrict__ coef,
                                                        const float* __restrict__ dis,
                                                        ucharT* __restrict__ C8, int n,
                                                        int mode) {
    __shared__ uint4 Wt[2048];          // 32 KB, bf16 swizzled (prestaged layout)
    int t = threadIdx.x;
    int wave = t >> 6, lane = t & 63;
    int l4 = lane >> 4;
    int lm = lane & 15;

    {
        const uint4* ws = reinterpret_cast<const uint4*>(Wt8);
        #pragma unroll
        for (int i = 0; i < 8; ++i) Wt[t + i * 256] = ws[t + i * 256];
    }
    __syncthreads();

    int rowBase = blockIdx.x * 64 + wave * 16;
    int ar = rowBase + lm;
    int arc = min(ar, n - 1);

    bf16x8 af[4];
    if (mode == 2) {
        float a = aggx[arc];
        #pragma unroll
        for (int kb = 0; kb < 4; ++kb) {
            int k0 = kb * 32 + l4 * 8;
            float4 sc0 = *reinterpret_cast<const float4*>(coef + k0);
            float4 sc1 = *reinterpret_cast<const float4*>(coef + k0 + 4);
            float4 sh0 = *reinterpret_cast<const float4*>(coef + HF + k0);
            float4 sh1 = *reinterpret_cast<const float4*>(coef + HF + k0 + 4);
            float scv[8] = {sc0.x, sc0.y, sc0.z, sc0.w, sc1.x, sc1.y, sc1.z, sc1.w};
            float shv[8] = {sh0.x, sh0.y, sh0.z, sh0.w, sh1.x, sh1.y, sh1.z, sh1.w};
            bf16x8 o;
            #pragma unroll
            for (int j = 0; j < 8; ++j) {
                float f = fmaxf(a * scv[j] + shv[j], 0.f);
                o[j] = (short)f2bf(f);
            }
            af[kb] = o;
        }
    } else {
        #pragma unroll
        for (int kb = 0; kb < 4; ++kb) {
            int k0 = kb * 32 + l4 * 8;
            const ushortT* ap = A + ((size_t)(k0 >> 4) * n + arc) * SLC + (k0 & 15);
            bf16x8 v = *reinterpret_cast<const bf16x8*>(ap);
            {
                float4 sc0 = *reinterpret_cast<const float4*>(coef + k0);
                float4 sc1 = *reinterpret_cast<const float4*>(coef + k0 + 4);
                float4 sh0 = *reinterpret_cast<const float4*>(coef + HF + k0);
                float4 sh1 = *reinterpret_cast<const float4*>(coef + HF + k0 + 4);
                float scv[8] = {sc0.x, sc0.y, sc0.z, sc0.w, sc1.x, sc1.y, sc1.z, sc1.w};
                float shv[8] = {sh0.x, sh0.y, sh0.z, sh0.w, sh1.x, sh1.y, sh1.z, sh1.w};
                bf16x8 o;
                #pragma unroll
                for (int j = 0; j < 8; ++j) {
                    float f = bf2f((uintT)(ushortT)v[j]);
                    f = fmaxf(f * scv[j] + shv[j], 0.f);
                    o[j] = (short)f2bf(f);
                }
                v = o;
            }
            af[kb] = v;
        }
    }

    f32x4 acc[8];
    #pragma unroll
    for (int ct = 0; ct < 8; ++ct) acc[ct] = (f32x4){0.f, 0.f, 0.f, 0.f};

    #pragma unroll
    for (int ct = 0; ct < 8; ++ct) {
        int col = ct * 16 + lm;
        int rowbyte = col << 8;
        int swz = (col & 7) << 4;
        #pragma unroll
        for (int kb = 0; kb < 4; ++kb) {
            int off = ((kb * 64 + l4 * 16) ^ swz);
            bf16x8 bf = *reinterpret_cast<const bf16x8*>((const char*)Wt + rowbyte + off);
            acc[ct] = __builtin_amdgcn_mfma_f32_16x16x32_bf16(af[kb], bf, acc[ct], 0, 0, 0);
        }
    }

    int rbase = rowBase + l4 * 4;
    float4 d4;
    if (rbase <= n - 4) {
        d4 = *reinterpret_cast<const float4*>(dis + rbase);
    } else {
        float tmp4[4];
        #pragma unroll
        for (int r = 0; r < 4; ++r) tmp4[r] = (rbase + r < n) ? dis[rbase + r] : 0.f;
        d4 = make_float4(tmp4[0], tmp4[1], tmp4[2], tmp4[3]);
    }
    const float* dd = (const float*)&d4;
    #pragma unroll
    for (int ct = 0; ct < 8; ++ct) {
        #pragma unroll
        for (int r = 0; r < 4; ++r) {
            float v = acc[ct][r] * dd[r];
            float o = __shfl_xor(v, 1);
            uintT pk = fp8_enc2(v, o);
            pk |= __shfl_xor(pk, 2) << 16;
            int row = rbase + r;
            if ((lane & 3) == 0 && row < n) {
                *(uintT*)(C8 + ((size_t)ct * n + row) * SLC + lm) = pk;   // slice = ct
            }
        }
    }
}

// ---------------- XCD-sliced CSR gather + fused BN stats ----------------
// slice = blockIdx & 7 (consecutive blocks round-robin XCDs -> slice pinned to XCD;
// per-XCD working set = n*16 fp8 = 1.6 MB, L2-resident). One lane = one (node, slice).

__global__ __launch_bounds__(256) void gather_stats_kernel(const ucharT* __restrict__ h8T,
                                                           const int* __restrict__ rowptr,
                                                           const int* __restrict__ csr_src,
                                                           const float* __restrict__ dis,
                                                           ushortT* __restrict__ aggT,
                                                           float* __restrict__ partial,
                                                           int n) {
    int t = threadIdx.x;
    int s = blockIdx.x & 7;
    int node = (blockIdx.x >> 3) * 256 + t;
    const ucharT* base = h8T + (size_t)s * n * SLC;

    float a[16];
    #pragma unroll
    for (int i = 0; i < 16; ++i) a[i] = 0.f;

    if (node < n) {
        uint4 v = *reinterpret_cast<const uint4*>(base + (size_t)node * SLC);  // self loop
        fp8_acc16(a, v);
        int beg = rowptr[node], end = rowptr[node + 1];
        for (int j = beg; j < end; ++j) {
            int srcn = csr_src[j];
            uint4 w = *reinterpret_cast<const uint4*>(base + (size_t)srcn * SLC);
            fp8_acc16(a, w);
        }
        float dd = dis[node];
        #pragma unroll
        for (int i = 0; i < 16; ++i) a[i] *= dd;
        uint4 o1, o2;
        o1.x = pack2(a[0], a[1]);   o1.y = pack2(a[2], a[3]);
        o1.z = pack2(a[4], a[5]);   o1.w = pack2(a[6], a[7]);
        o2.x = pack2(a[8], a[9]);   o2.y = pack2(a[10], a[11]);
        o2.z = pack2(a[12], a[13]); o2.w = pack2(a[14], a[15]);
        uint4* dst = reinterpret_cast<uint4*>(aggT + ((size_t)s * n + node) * SLC);
        dst[0] = o1; dst[1] = o2;
    }

    // block stats: each lane's a[] is one node's values for this slice's 16 cols
    __shared__ float red[4][32];
    int wv = t >> 6, ln = t & 63;
    #pragma unroll
    for (int i = 0; i < 16; ++i) {
        float si = a[i], qi = a[i] * a[i];
        for (int o = 32; o > 0; o >>= 1) {
            si += __shfl_down(si, o);
            qi += __shfl_down(qi, o);
        }
        if (ln == 0) { red[wv][i] = si; red[wv][16 + i] = qi; }
    }
    __syncthreads();
    if (t < 32) {
        partial[(size_t)blockIdx.x * 32 + t] =
            red[0][t] + red[1][t] + red[2][t] + red[3][t];
    }
}

// reduce partial[ngrp*8][32] -> partial2[RBLK][256]; t = slice*32 + o
__global__ __launch_bounds__(256) void reduce128_kernel(const float* __restrict__ partial,
                                                        float* __restrict__ partial2, int ngrp) {
    int t = threadIdx.x, b = blockIdx.x;
    int s = t >> 5, o = t & 31;
    float acc = 0.f;
    for (int j = b; j < ngrp; j += RBLK) acc += partial[(size_t)(j * 8 + s) * 32 + o];
    partial2[b * 256 + t] = acc;
}

__global__ void bn_coef_kernel(const float* __restrict__ partial2, const float* __restrict__ g,
                               const float* __restrict__ beta, float* __restrict__ coef,
                               float invn) {
    __shared__ float st[256];
    int t = threadIdx.x;    // 256
    float a = 0.f;
    #pragma unroll 8
    for (int b = 0; b < RBLK; ++b) a += partial2[b * 256 + t];
    st[t] = a;
    __syncthreads();
    if (t < 128) {
        int sl = t >> 4, c = t & 15;
        float m = st[sl * 32 + c] * invn;
        float v = st[sl * 32 + 16 + c] * invn - m * m;
        float sc = g[t] * rsqrtf(v + BN_EPS);
        coef[t] = sc;
        coef[HF + t] = beta[t] - m * sc;
    }
}

// ---------------- pooling (fused BN+ReLU of layer 2, slice-major input) ----------------

__global__ void starts_kernel(const int* __restrict__ batch, int* __restrict__ starts,
                              float* __restrict__ pooled, int n) {
    int g = threadIdx.x;
    if (g <= NG) {
        int lo = 0, hi = n;
        while (lo < hi) {
            int mid = (lo + hi) >> 1;
            if (batch[mid] < g) lo = mid + 1; else hi = mid;
        }
        starts[g] = lo;
    }
    for (int i = threadIdx.x; i < NG * HF; i += 128) pooled[i] = 0.f;
}

__global__ void pool_kernel(const ushortT* __restrict__ hT, const float* __restrict__ coef,
                            const int* __restrict__ starts, float* __restrict__ pooled, int n) {
    int g = blockIdx.x >> 4;
    int p = blockIdx.x & 15;
    int lane = threadIdx.x;          // 64: global cols 2*lane, 2*lane+1
    int sl = lane >> 3;              // slice
    int ci = (lane * 2) & 15;        // col within slice
    const ushortT* hp = hT + (size_t)sl * n * SLC + ci;
    float sc0 = coef[lane * 2],      sc1 = coef[lane * 2 + 1];
    float sh0 = coef[HF + lane * 2], sh1 = coef[HF + lane * 2 + 1];
    int s = starts[g], e = starts[g + 1];
    int len = e - s;
    int chunk = (len + 15) >> 4;
    int r0 = s + p * chunk;
    int r1 = min(e, r0 + chunk);
    float a0 = 0.f, a1 = 0.f;
    for (int r = r0; r < r1; ++r) {
        uintT v = *reinterpret_cast<const uintT*>(hp + (size_t)r * SLC);
        a0 += fmaxf(bf2f(v & 0xffff) * sc0 + sh0, 0.f);
        a1 += fmaxf(bf2f_hi(v) * sc1 + sh1, 0.f);
    }
    if (r1 > r0) {
        atomicAdd(&pooled[g * HF + lane * 2], a0);
        atomicAdd(&pooled[g * HF + lane * 2 + 1], a1);
    }
}

// ---------------- head ----------------

__global__ __launch_bounds__(1024) void head_kernel(const float* __restrict__ pooled,
                                                    const int* __restrict__ starts,
                                                    const float* __restrict__ Wl,
                                                    const float* __restrict__ bl,
                                                    const float* __restrict__ Wo,
                                                    const float* __restrict__ bo,
                                                    float* __restrict__ out) {
    __shared__ float P[NG][HF];
    __shared__ float T[NG][HF];
    int t = threadIdx.x;
    for (int i = t; i < NG * HF; i += 1024) {
        int g = i >> 7;
        float cnt = fmaxf((float)(starts[g + 1] - starts[g]), 1.0f);
        P[g][i & 127] = pooled[i] / cnt;
    }
    __syncthreads();
    for (int i = t; i < NG * HF; i += 1024) {
        int g = i >> 7, j = i & 127;
        float acc = bl[j];
        for (int k = 0; k < HF; ++k) acc += P[g][k] * Wl[k * HF + j];
        T[g][j] = fmaxf(acc, 0.f);
    }
    __syncthreads();
    int g = t >> 4, o = t & 15;
    float acc = bo[o];
    for (int k = 0; k < HF; ++k) acc += T[g][k] * Wo[k * OUTF + o];
    out[t] = acc;
}

// ---------------- launch ----------------

extern "C" void kernel_launch(void* const* d_in, const int* in_sizes, int n_in,
                              void* d_out, int out_size, void* d_ws, size_t ws_size,
                              hipStream_t stream) {
    const float* x     = (const float*)d_in[0];
    const int*   ei    = (const int*)d_in[1];
    const int*   batch = (const int*)d_in[2];
    const float* W0 = (const float*)d_in[3];
    const float* g0 = (const float*)d_in[5];
    const float* be0 = (const float*)d_in[6];
    const float* W1 = (const float*)d_in[7];
    const float* g1 = (const float*)d_in[9];
    const float* be1 = (const float*)d_in[10];
    const float* W2 = (const float*)d_in[11];
    const float* g2 = (const float*)d_in[13];
    const float* be2 = (const float*)d_in[14];
    const float* Wl = (const float*)d_in[15];
    const float* bl = (const float*)d_in[16];
    const float* Wo = (const float*)d_in[17];
    const float* bo = (const float*)d_in[18];

    const int n = in_sizes[0];
    const int E = in_sizes[1] / 2;
    const int* srcI = ei;
    const int* dstI = ei + E;
    const int nbkt = (n + PBSZ - 1) >> PBSH;            // 782 for n=100000 (<=1024)
    const int nblk = (E + CHUNK - 1) / CHUNK;           // 391
    const int nblk1 = (n + 255) / 256;                  // gather1 blocks
    const int ngrp = (n + 255) / 256;                   // gather node groups (391)

    ushortT* bufA = (ushortT*)d_ws;                      // n*HF bf16 (aggT, slice-major)
    ushortT* bufB = bufA + (size_t)n * HF;               // n*HF bytes fp8 (h8T, slice-major)
    ucharT* bufB8 = (ucharT*)bufB;
    float* dis    = (float*)(bufB + (size_t)n * HF);     // n
    float* xp     = dis + n;                             // n
    float* aggx   = xp + n;                              // n
    float* coef   = aggx + n;                            // 2*HF
    float* pooled = coef + 2 * HF;                       // NG*HF
    int* rowptr   = (int*)(pooled + NG * HF);            // n+1
    int* csr_src  = rowptr + n + 1;                      // E
    uintT* tmp    = (uintT*)(csr_src + E);               // E
    int* bhistB   = (int*)(tmp + E);                     // nblk*1024
    int* lbase    = bhistB + (size_t)nblk * 1024;        // nblk*1024
    int* total    = lbase + (size_t)nblk * 1024;         // 1024
    int* bbase    = total + 1024;                        // nbkt+1
    int* starts   = bbase + 1025;                        // NG+1
    float* partial = (float*)(starts + NG + 1);          // ngrp*8*32
    float* partial2 = partial + (size_t)ngrp * 8 * 32;   // RBLK*256
    float* partial1 = partial2 + RBLK * 256;             // nblk1*2
    ushortT* wbuf1 = (ushortT*)(partial1 + (size_t)nblk1 * 2 + 2);  // 16384 bf16
    ushortT* wbuf2 = wbuf1 + 16384;                      // 16384 bf16

    // ---- CSR build (atomic-free, 5 kernels) ----
    bhist_kernel<<<nblk, 1024, 0, stream>>>(dstI, bhistB, E, nbkt);
    bscan_blocks_kernel<<<(nbkt + 3) / 4, 256, 0, stream>>>(bhistB, lbase, total, nblk, nbkt);
    bscan_base_kernel<<<1, 1024, 0, stream>>>(total, bbase, nbkt);
    bscatter_kernel<<<nblk, 1024, 0, stream>>>(srcI, dstI, bbase, lbase, tmp, E, nbkt);
    breorder_kernel<<<nbkt, 256, 0, stream>>>(tmp, bbase, x, rowptr, csr_src, dis, xp, n, nbkt);

    // ---- layer 0 (rank-1): fused gather+stats -> coef0 ----
    gather1_kernel<<<nblk1, 256, 0, stream>>>(xp, rowptr, csr_src, dis, aggx, partial1, n);
    coef0_kernel<<<1, 128, 0, stream>>>(partial1, nblk1, W0, g0, be0, coef, 1.0f / n);

    // ---- W prep (both layers) ----
    wprep2_kernel<<<128, 256, 0, stream>>>(W1, W2, wbuf1, wbuf2);

    // ---- layer 1 ----
    gemm_mfma_kernel<<<(n + 63) / 64, 256, 0, stream>>>(bufA, aggx, wbuf1, coef, dis, bufB8, n, 2);
    gather_stats_kernel<<<ngrp * 8, 256, 0, stream>>>(bufB8, rowptr, csr_src, dis, bufA, partial, n);
    reduce128_kernel<<<RBLK, 256, 0, stream>>>(partial, partial2, ngrp);
    bn_coef_kernel<<<1, 256, 0, stream>>>(partial2, g1, be1, coef, 1.0f / n);

    // ---- layer 2 ----
    gemm_mfma_kernel<<<(n + 63) / 64, 256, 0, stream>>>(bufA, aggx, wbuf2, coef, dis, bufB8, n, 1);
    gather_stats_kernel<<<ngrp * 8, 256, 0, stream>>>(bufB8, rowptr, csr_src, dis, bufA, partial, n);
    reduce128_kernel<<<RBLK, 256, 0, stream>>>(partial, partial2, ngrp);
    bn_coef_kernel<<<1, 256, 0, stream>>>(partial2, g2, be2, coef, 1.0f / n);

    // ---- pool (fused BN+ReLU) + head ----
    starts_kernel<<<1, 128, 0, stream>>>(batch, starts, pooled, n);
    pool_kernel<<<NG * 16, 64, 0, stream>>>(bufA, coef, starts, pooled, n);
    head_kernel<<<1, 1024, 0, stream>>>(pooled, starts, Wl, bl, Wo, bo, (float*)d_out);
}

// Round 18
// 300.293 us; speedup vs baseline: 1.4595x; 1.4595x over previous
//
#include <hip/hip_runtime.h>

#define HF 128
#define OUTF 16
#define NG 64
#define PBSH 7             // bucket = dst >> 7 (PB = 128 nodes/bucket)
#define PBSZ 128
#define CHUNK 4096         // edges per histogram/scatter block (391 blocks)
#define STAGE 4608         // reorder LDS stage entries (avg bucket ~2046)
#define GBLK 2048          // gather grid blocks (grid-stride)
#define RBLK 128           // stats reduce blocks
#define BN_EPS 1e-5f

typedef unsigned short ushortT;
typedef unsigned int uintT;
typedef unsigned char ucharT;
typedef __attribute__((ext_vector_type(8))) short bf16x8;
typedef __attribute__((ext_vector_type(4))) float f32x4;
typedef __attribute__((ext_vector_type(2))) float f32x2;

__device__ __forceinline__ float bf2f(uintT u) {
    union { uintT i; float f; } c; c.i = u << 16; return c.f;
}
__device__ __forceinline__ float bf2f_hi(uintT u) {
    union { uintT i; float f; } c; c.i = u & 0xffff0000u; return c.f;
}
__device__ __forceinline__ uintT f2bf(float f) {
    union { float f; uintT i; } c; c.f = f;
    uintT u = c.i;
    return (u + 0x7fffu + ((u >> 16) & 1u)) >> 16;
}
__device__ __forceinline__ uintT pack2(float a, float b) {
    return f2bf(a) | (f2bf(b) << 16);
}

// HW OCP e4m3 conversions (gfx950)
__device__ __forceinline__ uintT fp8_enc2(float a, float b) {
    return (uintT)__builtin_amdgcn_cvt_pk_fp8_f32(a, b, 0, false) & 0xffffu;
}
__device__ __forceinline__ void fp8_acc8(float* a, uint2 v) {
    f32x2 f;
    f = __builtin_amdgcn_cvt_pk_f32_fp8((int)v.x, false); a[0] += f.x; a[1] += f.y;
    f = __builtin_amdgcn_cvt_pk_f32_fp8((int)v.x, true);  a[2] += f.x; a[3] += f.y;
    f = __builtin_amdgcn_cvt_pk_f32_fp8((int)v.y, false); a[4] += f.x; a[5] += f.y;
    f = __builtin_amdgcn_cvt_pk_f32_fp8((int)v.y, true);  a[6] += f.x; a[7] += f.y;
}

// ---------------- CSR build, atomic-free (global), 5 kernels ----------------

__global__ __launch_bounds__(1024) void bhist_kernel(const int* __restrict__ dst,
                                                     int* __restrict__ bhistB,
                                                     int E, int nbkt) {
    __shared__ int h[1024];
    int t = threadIdx.x, blk = blockIdx.x;
    if (t < 1024) h[t] = 0;
    __syncthreads();
    int e0 = blk * CHUNK, e1 = min(E, e0 + CHUNK);
    for (int e = e0 + t; e < e1; e += 1024) atomicAdd(&h[dst[e] >> PBSH], 1);
    __syncthreads();
    if (t < nbkt) bhistB[blk * 1024 + t] = h[t];
}

// Wave-per-bucket parallel scan across blocks: lbase[blk][bkt], total[bkt].
__global__ __launch_bounds__(256) void bscan_blocks_kernel(const int* __restrict__ bhistB,
                                                           int* __restrict__ lbase,
                                                           int* __restrict__ total,
                                                           int nblk, int nbkt) {
    int bkt = blockIdx.x * 4 + (threadIdx.x >> 6);
    int lane = threadIdx.x & 63;
    if (bkt >= nbkt) return;
    int run = 0;
    for (int base = 0; base < nblk; base += 64) {
        int blk = base + lane;
        int v = (blk < nblk) ? bhistB[(size_t)blk * 1024 + bkt] : 0;
        int pre = v;
        #pragma unroll
        for (int o = 1; o < 64; o <<= 1) {
            int u = __shfl_up(pre, o);
            if (lane >= o) pre += u;
        }
        if (blk < nblk) lbase[(size_t)blk * 1024 + bkt] = run + pre - v;
        run += __shfl(pre, 63);
    }
    if (lane == 0) total[bkt] = run;
}

__global__ __launch_bounds__(1024) void bscan_base_kernel(const int* __restrict__ total,
                                                          int* __restrict__ bbase, int nbkt) {
    __shared__ int sc[1024];
    int t = threadIdx.x;
    int v = (t < nbkt) ? total[t] : 0;
    sc[t] = v;
    __syncthreads();
    for (int o = 1; o < 1024; o <<= 1) {
        int add = (t >= o) ? sc[t - o] : 0;
        __syncthreads();
        sc[t] += add;
        __syncthreads();
    }
    if (t < nbkt) {
        bbase[t] = sc[t] - v;
        if (t == nbkt - 1) bbase[nbkt] = sc[t];
    }
}

__global__ __launch_bounds__(1024) void bscatter_kernel(const int* __restrict__ src,
                                                        const int* __restrict__ dst,
                                                        const int* __restrict__ bbase,
                                                        const int* __restrict__ lbase,
                                                        uintT* __restrict__ tmp,
                                                        int E, int nbkt) {
    __shared__ int cur[1024];
    int t = threadIdx.x, blk = blockIdx.x;
    if (t < nbkt) cur[t] = bbase[t] + lbase[(size_t)blk * 1024 + t];
    __syncthreads();
    int e0 = blk * CHUNK, e1 = min(E, e0 + CHUNK);
    for (int e = e0 + t; e < e1; e += 1024) {
        int d = dst[e];
        int bkt = d >> PBSH;
        int pos = atomicAdd(&cur[bkt], 1);
        tmp[pos] = ((uintT)(d & (PBSZ - 1)) << 18) | (uintT)src[e];
    }
}

__global__ __launch_bounds__(256) void breorder_kernel(const uintT* __restrict__ tmp,
                                                       const int* __restrict__ bbase,
                                                       const float* __restrict__ x,
                                                       int* __restrict__ rowptr,
                                                       int* __restrict__ csr_src,
                                                       float* __restrict__ dis,
                                                       float* __restrict__ xp,
                                                       int n, int nbkt) {
    __shared__ int lcnt[PBSZ];
    __shared__ int sc[PBSZ];
    __shared__ int lcur[PBSZ];
    __shared__ int stage[STAGE];
    int b = blockIdx.x, t = threadIdx.x;
    int n0 = b << PBSH;
    if (n0 >= n) return;
    int start = bbase[b], end = bbase[b + 1];
    int cnt = end - start;
    if (t < PBSZ) lcnt[t] = 0;
    __syncthreads();
    for (int i = t; i < cnt; i += 256) atomicAdd(&lcnt[tmp[start + i] >> 18], 1);
    __syncthreads();
    int v = (t < PBSZ) ? lcnt[t] : 0;
    if (t < PBSZ) sc[t] = v;
    __syncthreads();
    for (int o = 1; o < PBSZ; o <<= 1) {
        int add = (t < PBSZ && t >= o) ? sc[t - o] : 0;
        __syncthreads();
        if (t < PBSZ) sc[t] += add;
        __syncthreads();
    }
    if (t < PBSZ) {
        int pre = sc[t] - v;
        lcur[t] = pre;
        int node = n0 + t;
        if (node < n) {
            rowptr[node] = start + pre;
            float d = rsqrtf((float)v + 1.0f);      // +1 = self loop
            dis[node] = d;
            xp[node] = d * x[node];
        }
    }
    if (b == nbkt - 1 && t == 0) rowptr[n] = end;
    __syncthreads();
    if (cnt <= STAGE) {
        for (int i = t; i < cnt; i += 256) {
            uintT p = tmp[start + i];
            int pos = atomicAdd(&lcur[p >> 18], 1);
            stage[pos] = (int)(p & 0x3ffffu);
        }
        __syncthreads();
        for (int i = t; i < cnt; i += 256) csr_src[start + i] = stage[i];
    } else {
        for (int i = t; i < cnt; i += 256) {
            uintT p = tmp[start + i];
            int pos = atomicAdd(&lcur[p >> 18], 1);
            csr_src[start + pos] = (int)(p & 0x3ffffu);
        }
    }
}

// ---------------- layer 0: scalar gather + fused block stats ----------------

__global__ __launch_bounds__(256) void gather1_kernel(const float* __restrict__ xp,
                                                      const int* __restrict__ rowptr,
                                                      const int* __restrict__ csr_src,
                                                      const float* __restrict__ dis,
                                                      float* __restrict__ aggx,
                                                      float* __restrict__ partial1, int n) {
    int t = threadIdx.x;
    int i = blockIdx.x * 256 + t;
    float v = 0.f;
    if (i < n) {
        float acc = xp[i];                // self loop
        int e = rowptr[i + 1];
        for (int j = rowptr[i]; j < e; ++j) acc += xp[csr_src[j]];
        v = acc * dis[i];
        aggx[i] = v;
    }
    float s = v, ss = v * v;
    for (int o = 32; o > 0; o >>= 1) { s += __shfl_down(s, o); ss += __shfl_down(ss, o); }
    __shared__ float r2[2][4];
    int wv = t >> 6, ln = t & 63;
    if (ln == 0) { r2[0][wv] = s; r2[1][wv] = ss; }
    __syncthreads();
    if (t == 0) {
        partial1[blockIdx.x * 2]     = r2[0][0] + r2[0][1] + r2[0][2] + r2[0][3];
        partial1[blockIdx.x * 2 + 1] = r2[1][0] + r2[1][1] + r2[1][2] + r2[1][3];
    }
}

__global__ void coef0_kernel(const float* __restrict__ partial1, int nblk1,
                             const float* __restrict__ W0, const float* __restrict__ g,
                             const float* __restrict__ beta, float* __restrict__ coef,
                             float invn) {
    __shared__ float rs[128], rss[128];
    int t = threadIdx.x;    // 128
    float s = 0.f, ss = 0.f;
    for (int k = t; k < nblk1; k += 128) { s += partial1[2 * k]; ss += partial1[2 * k + 1]; }
    rs[t] = s; rss[t] = ss;
    __syncthreads();
    for (int o = 64; o > 0; o >>= 1) {
        if (t < o) { rs[t] += rs[t + o]; rss[t] += rss[t + o]; }
        __syncthreads();
    }
    float m = rs[0] * invn;
    float var = rss[0] * invn - m * m;
    float w = W0[t];
    float sc = g[t] * w * rsqrtf(var * w * w + BN_EPS);
    coef[t] = sc;
    coef[HF + t] = beta[t] - m * sc;
}

// ---------------- W pre-conversion (both layers, one kernel) ----------------

__global__ void wprep2_kernel(const float* __restrict__ W1, const float* __restrict__ W2,
                              ushortT* __restrict__ Wt1, ushortT* __restrict__ Wt2) {
    int i = blockIdx.x * 256 + threadIdx.x;     // 128 blocks -> 32768
    const float* W = (i < 16384) ? W1 : W2;
    ushortT* Wt = (i < 16384) ? Wt1 : Wt2;
    int ii = i & 16383;
    int k = ii >> 7, j = ii & 127;
    int byteoff = (j << 8) + ((k << 1) ^ ((j & 7) << 4));
    *(ushortT*)((char*)Wt + byteoff) = (ushortT)f2bf(W[ii]);
}

// ---------------- MFMA GEMM: C8[n,128] = fp8(dis[row] * (act(A)[n,128] @ W[128,128])) ----

__global__ __launch_bounds__(256) void gemm_mfma_kernel(const ushortT* __restrict__ A,
                                                        const float* __restrict__ aggx,
                                                        const ushortT* __restrict__ Wt8,
                                                        const float* __restrict__ coef,
                                                        const float* __restrict__ dis,
                                                        ucharT* __restrict__ C8, int n,
                                                        int mode) {
    __shared__ uint4 Wt[2048];          // 32 KB, bf16 swizzled (prestaged layout)
    int t = threadIdx.x;
    int wave = t >> 6, lane = t & 63;
    int l4 = lane >> 4;
    int lm = lane & 15;

    {
        const uint4* ws = reinterpret_cast<const uint4*>(Wt8);
        #pragma unroll
        for (int i = 0; i < 8; ++i) Wt[t + i * 256] = ws[t + i * 256];
    }
    __syncthreads();

    int rowBase = blockIdx.x * 64 + wave * 16;
    int ar = rowBase + lm;
    int arc = min(ar, n - 1);

    bf16x8 af[4];
    if (mode == 2) {
        float a = aggx[arc];
        #pragma unroll
        for (int kb = 0; kb < 4; ++kb) {
            int k0 = kb * 32 + l4 * 8;
            float4 sc0 = *reinterpret_cast<const float4*>(coef + k0);
            float4 sc1 = *reinterpret_cast<const float4*>(coef + k0 + 4);
            float4 sh0 = *reinterpret_cast<const float4*>(coef + HF + k0);
            float4 sh1 = *reinterpret_cast<const float4*>(coef + HF + k0 + 4);
            float scv[8] = {sc0.x, sc0.y, sc0.z, sc0.w, sc1.x, sc1.y, sc1.z, sc1.w};
            float shv[8] = {sh0.x, sh0.y, sh0.z, sh0.w, sh1.x, sh1.y, sh1.z, sh1.w};
            bf16x8 o;
            #pragma unroll
            for (int j = 0; j < 8; ++j) {
                float f = fmaxf(a * scv[j] + shv[j], 0.f);
                o[j] = (short)f2bf(f);
            }
            af[kb] = o;
        }
    } else {
        #pragma unroll
        for (int kb = 0; kb < 4; ++kb) {
            int k0 = kb * 32 + l4 * 8;
            bf16x8 v = *reinterpret_cast<const bf16x8*>(A + (size_t)arc * HF + k0);
            if (mode == 1) {
                float4 sc0 = *reinterpret_cast<const float4*>(coef + k0);
                float4 sc1 = *reinterpret_cast<const float4*>(coef + k0 + 4);
                float4 sh0 = *reinterpret_cast<const float4*>(coef + HF + k0);
                float4 sh1 = *reinterpret_cast<const float4*>(coef + HF + k0 + 4);
                float scv[8] = {sc0.x, sc0.y, sc0.z, sc0.w, sc1.x, sc1.y, sc1.z, sc1.w};
                float shv[8] = {sh0.x, sh0.y, sh0.z, sh0.w, sh1.x, sh1.y, sh1.z, sh1.w};
                bf16x8 o;
                #pragma unroll
                for (int j = 0; j < 8; ++j) {
                    float f = bf2f((uintT)(ushortT)v[j]);
                    f = fmaxf(f * scv[j] + shv[j], 0.f);
                    o[j] = (short)f2bf(f);
                }
                v = o;
            }
            af[kb] = v;
        }
    }

    f32x4 acc[8];
    #pragma unroll
    for (int ct = 0; ct < 8; ++ct) acc[ct] = (f32x4){0.f, 0.f, 0.f, 0.f};

    #pragma unroll
    for (int ct = 0; ct < 8; ++ct) {
        int col = ct * 16 + lm;
        int rowbyte = col << 8;
        int swz = (col & 7) << 4;
        #pragma unroll
        for (int kb = 0; kb < 4; ++kb) {
            int off = ((kb * 64 + l4 * 16) ^ swz);
            bf16x8 bf = *reinterpret_cast<const bf16x8*>((const char*)Wt + rowbyte + off);
            acc[ct] = __builtin_amdgcn_mfma_f32_16x16x32_bf16(af[kb], bf, acc[ct], 0, 0, 0);
        }
    }

    int rbase = rowBase + l4 * 4;
    float4 d4;
    if (rbase <= n - 4) {
        d4 = *reinterpret_cast<const float4*>(dis + rbase);
    } else {
        float tmp4[4];
        #pragma unroll
        for (int r = 0; r < 4; ++r) tmp4[r] = (rbase + r < n) ? dis[rbase + r] : 0.f;
        d4 = make_float4(tmp4[0], tmp4[1], tmp4[2], tmp4[3]);
    }
    const float* dd = (const float*)&d4;
    #pragma unroll
    for (int ct = 0; ct < 8; ++ct) {
        #pragma unroll
        for (int r = 0; r < 4; ++r) {
            float v = acc[ct][r] * dd[r];
            float o = __shfl_xor(v, 1);
            uintT pk = fp8_enc2(v, o);
            pk |= __shfl_xor(pk, 2) << 16;
            int row = rbase + r;
            if ((lane & 3) == 0 && row < n) {
                *(uintT*)(C8 + (size_t)row * HF + ct * 16 + lm) = pk;
            }
        }
    }
}

// ---------------- CSR gather (fp8 rows, wide) + fused BN stats partials ----------------

__global__ __launch_bounds__(256) void gather_stats_kernel(const ucharT* __restrict__ h8,
                                                           const int* __restrict__ rowptr,
                                                           const int* __restrict__ csr_src,
                                                           const float* __restrict__ dis,
                                                           ushortT* __restrict__ agg,
                                                           float* __restrict__ partial,
                                                           int n) {
    __shared__ float part[4][256];
    int t = threadIdx.x;
    int wave = t >> 6, lane = t & 63;
    int grp = lane >> 4;          // 0..3: edge slot
    int l = lane & 15;            // col block: cols l*8..l*8+7
    float s[8], ss[8];
    #pragma unroll
    for (int i = 0; i < 8; ++i) { s[i] = 0.f; ss[i] = 0.f; }

    for (int node = blockIdx.x * 4 + wave; node < n; node += GBLK * 4) {
        int beg = rowptr[node], end = rowptr[node + 1];
        float a[8];
        #pragma unroll
        for (int i = 0; i < 8; ++i) a[i] = 0.f;
        if (grp == 0) {           // self loop
            uint2 v = *reinterpret_cast<const uint2*>(h8 + (size_t)node * HF + l * 8);
            fp8_acc8(a, v);
        }
        for (int base = beg; base < end; base += 64) {
            int idx = base + lane;
            int sj = (idx < end) ? csr_src[idx] : 0;
            int cnt = min(64, end - base);
            for (int j = 0; j < cnt; j += 4) {
                int e = j + grp;
                int srcn = __shfl(sj, e < 64 ? e : 63);
                if (e < cnt) {
                    uint2 v = *reinterpret_cast<const uint2*>(h8 + (size_t)srcn * HF + l * 8);
                    fp8_acc8(a, v);
                }
            }
        }
        #pragma unroll
        for (int i = 0; i < 8; ++i) {
            a[i] += __shfl_xor(a[i], 16);
            a[i] += __shfl_xor(a[i], 32);
        }
        if (grp == 0) {
            float dd = dis[node];
            #pragma unroll
            for (int i = 0; i < 8; ++i) {
                a[i] *= dd;
                s[i] += a[i];
                ss[i] += a[i] * a[i];
            }
            uint4 o;
            o.x = pack2(a[0], a[1]);
            o.y = pack2(a[2], a[3]);
            o.z = pack2(a[4], a[5]);
            o.w = pack2(a[6], a[7]);
            *reinterpret_cast<uint4*>(agg + (size_t)node * HF + l * 8) = o;
        }
    }

    if (grp == 0) {
        #pragma unroll
        for (int i = 0; i < 8; ++i) {
            part[wave][l * 8 + i] = s[i];
            part[wave][128 + l * 8 + i] = ss[i];
        }
    }
    __syncthreads();
    float v = part[0][t] + part[1][t] + part[2][t] + part[3][t];
    partial[(size_t)blockIdx.x * 256 + t] = v;
}

// 128-block non-atomic reduce: partial[GBLK][256] -> partial2[RBLK][256]
__global__ __launch_bounds__(256) void reduce128_kernel(const float* __restrict__ partial,
                                                        float* __restrict__ partial2, int nblk) {
    int t = threadIdx.x, b = blockIdx.x;
    float acc = 0.f;
    for (int r = b; r < nblk; r += RBLK) acc += partial[(size_t)r * 256 + t];
    partial2[b * 256 + t] = acc;
}

__global__ void bn_coef_kernel(const float* __restrict__ partial2, const float* __restrict__ g,
                               const float* __restrict__ beta, float* __restrict__ coef,
                               float invn) {
    __shared__ float st[256];
    int t = threadIdx.x;    // 256
    float a = 0.f;
    #pragma unroll 8
    for (int b = 0; b < RBLK; ++b) a += partial2[b * 256 + t];
    st[t] = a;
    __syncthreads();
    if (t < 128) {
        float m = st[t] * invn;
        float v = st[128 + t] * invn - m * m;
        float sc = g[t] * rsqrtf(v + BN_EPS);
        coef[t] = sc;
        coef[HF + t] = beta[t] - m * sc;
    }
}

// ---------------- pooling (fused BN+ReLU of layer 2) ----------------

__global__ void starts_kernel(const int* __restrict__ batch, int* __restrict__ starts,
                              float* __restrict__ pooled, int n) {
    int g = threadIdx.x;
    if (g <= NG) {
        int lo = 0, hi = n;
        while (lo < hi) {
            int mid = (lo + hi) >> 1;
            if (batch[mid] < g) lo = mid + 1; else hi = mid;
        }
        starts[g] = lo;
    }
    for (int i = threadIdx.x; i < NG * HF; i += 128) pooled[i] = 0.f;
}

__global__ void pool_kernel(const ushortT* __restrict__ h, const float* __restrict__ coef,
                            const int* __restrict__ starts, float* __restrict__ pooled) {
    int g = blockIdx.x >> 4;
    int p = blockIdx.x & 15;
    int lane = threadIdx.x;
    float sc0 = coef[lane * 2],     sc1 = coef[lane * 2 + 1];
    float sh0 = coef[HF + lane * 2], sh1 = coef[HF + lane * 2 + 1];
    int s = starts[g], e = starts[g + 1];
    int len = e - s;
    int chunk = (len + 15) >> 4;
    int r0 = s + p * chunk;
    int r1 = min(e, r0 + chunk);
    float a0 = 0.f, a1 = 0.f;
    for (int r = r0; r < r1; ++r) {
        uintT v = *reinterpret_cast<const uintT*>(h + (size_t)r * HF + lane * 2);
        a0 += fmaxf(bf2f(v & 0xffff) * sc0 + sh0, 0.f);
        a1 += fmaxf(bf2f_hi(v) * sc1 + sh1, 0.f);
    }
    if (r1 > r0) {
        atomicAdd(&pooled[g * HF + lane * 2], a0);
        atomicAdd(&pooled[g * HF + lane * 2 + 1], a1);
    }
}

// ---------------- head ----------------

__global__ __launch_bounds__(1024) void head_kernel(const float* __restrict__ pooled,
                                                    const int* __restrict__ starts,
                                                    const float* __restrict__ Wl,
                                                    const float* __restrict__ bl,
                                                    const float* __restrict__ Wo,
                                                    const float* __restrict__ bo,
                                                    float* __restrict__ out) {
    __shared__ float P[NG][HF];
    __shared__ float T[NG][HF];
    int t = threadIdx.x;
    for (int i = t; i < NG * HF; i += 1024) {
        int g = i >> 7;
        float cnt = fmaxf((float)(starts[g + 1] - starts[g]), 1.0f);
        P[g][i & 127] = pooled[i] / cnt;
    }
    __syncthreads();
    for (int i = t; i < NG * HF; i += 1024) {
        int g = i >> 7, j = i & 127;
        float acc = bl[j];
        for (int k = 0; k < HF; ++k) acc += P[g][k] * Wl[k * HF + j];
        T[g][j] = fmaxf(acc, 0.f);
    }
    __syncthreads();
    int g = t >> 4, o = t & 15;
    float acc = bo[o];
    for (int k = 0; k < HF; ++k) acc += T[g][k] * Wo[k * OUTF + o];
    out[t] = acc;
}

// ---------------- launch ----------------

extern "C" void kernel_launch(void* const* d_in, const int* in_sizes, int n_in,
                              void* d_out, int out_size, void* d_ws, size_t ws_size,
                              hipStream_t stream) {
    const float* x     = (const float*)d_in[0];
    const int*   ei    = (const int*)d_in[1];
    const int*   batch = (const int*)d_in[2];
    const float* W0 = (const float*)d_in[3];
    const float* g0 = (const float*)d_in[5];
    const float* be0 = (const float*)d_in[6];
    const float* W1 = (const float*)d_in[7];
    const float* g1 = (const float*)d_in[9];
    const float* be1 = (const float*)d_in[10];
    const float* W2 = (const float*)d_in[11];
    const float* g2 = (const float*)d_in[13];
    const float* be2 = (const float*)d_in[14];
    const float* Wl = (const float*)d_in[15];
    const float* bl = (const float*)d_in[16];
    const float* Wo = (const float*)d_in[17];
    const float* bo = (const float*)d_in[18];

    const int n = in_sizes[0];
    const int E = in_sizes[1] / 2;
    const int* srcI = ei;
    const int* dstI = ei + E;
    const int nbkt = (n + PBSZ - 1) >> PBSH;            // 782 for n=100000 (<=1024)
    const int nblk = (E + CHUNK - 1) / CHUNK;           // 391
    const int nblk1 = (n + 255) / 256;                  // gather1 blocks

    ushortT* bufA = (ushortT*)d_ws;                      // n*HF bf16 (agg)
    ushortT* bufB = bufA + (size_t)n * HF;               // n*HF bytes used as fp8 (t')
    ucharT* bufB8 = (ucharT*)bufB;
    float* dis    = (float*)(bufB + (size_t)n * HF);     // n
    float* xp     = dis + n;                             // n
    float* aggx   = xp + n;                              // n
    float* coef   = aggx + n;                            // 2*HF
    float* pooled = coef + 2 * HF;                       // NG*HF
    int* rowptr   = (int*)(pooled + NG * HF);            // n+1
    int* csr_src  = rowptr + n + 1;                      // E
    uintT* tmp    = (uintT*)(csr_src + E);               // E
    int* bhistB   = (int*)(tmp + E);                     // nblk*1024
    int* lbase    = bhistB + (size_t)nblk * 1024;        // nblk*1024
    int* total    = lbase + (size_t)nblk * 1024;         // 1024
    int* bbase    = total + 1024;                        // nbkt+1
    int* starts   = bbase + 1025;                        // NG+1
    float* partial = (float*)(starts + NG + 1);          // GBLK*256
    float* partial2 = partial + (size_t)GBLK * 256;      // RBLK*256
    float* partial1 = partial2 + RBLK * 256;             // nblk1*2
    ushortT* wbuf1 = (ushortT*)(partial1 + (size_t)nblk1 * 2 + 2);  // 16384 bf16
    ushortT* wbuf2 = wbuf1 + 16384;                      // 16384 bf16

    // ---- CSR build (atomic-free, 5 kernels) ----
    bhist_kernel<<<nblk, 1024, 0, stream>>>(dstI, bhistB, E, nbkt);
    bscan_blocks_kernel<<<(nbkt + 3) / 4, 256, 0, stream>>>(bhistB, lbase, total, nblk, nbkt);
    bscan_base_kernel<<<1, 1024, 0, stream>>>(total, bbase, nbkt);
    bscatter_kernel<<<nblk, 1024, 0, stream>>>(srcI, dstI, bbase, lbase, tmp, E, nbkt);
    breorder_kernel<<<nbkt, 256, 0, stream>>>(tmp, bbase, x, rowptr, csr_src, dis, xp, n, nbkt);

    // ---- layer 0 (rank-1): fused gather+stats -> coef0 ----
    gather1_kernel<<<nblk1, 256, 0, stream>>>(xp, rowptr, csr_src, dis, aggx, partial1, n);
    coef0_kernel<<<1, 128, 0, stream>>>(partial1, nblk1, W0, g0, be0, coef, 1.0f / n);

    // ---- W prep (both layers) ----
    wprep2_kernel<<<128, 256, 0, stream>>>(W1, W2, wbuf1, wbuf2);

    // ---- layer 1 ----
    gemm_mfma_kernel<<<(n + 63) / 64, 256, 0, stream>>>(bufA, aggx, wbuf1, coef, dis, bufB8, n, 2);
    gather_stats_kernel<<<GBLK, 256, 0, stream>>>(bufB8, rowptr, csr_src, dis, bufA, partial, n);
    reduce128_kernel<<<RBLK, 256, 0, stream>>>(partial, partial2, GBLK);
    bn_coef_kernel<<<1, 256, 0, stream>>>(partial2, g1, be1, coef, 1.0f / n);

    // ---- layer 2 ----
    gemm_mfma_kernel<<<(n + 63) / 64, 256, 0, stream>>>(bufA, aggx, wbuf2, coef, dis, bufB8, n, 1);
    gather_stats_kernel<<<GBLK, 256, 0, stream>>>(bufB8, rowptr, csr_src, dis, bufA, partial, n);
    reduce128_kernel<<<RBLK, 256, 0, stream>>>(partial, partial2, GBLK);
    bn_coef_kernel<<<1, 256, 0, stream>>>(partial2, g2, be2, coef, 1.0f / n);

    // ---- pool (fused BN+ReLU) + head ----
    starts_kernel<<<1, 128, 0, stream>>>(batch, starts, pooled, n);
    pool_kernel<<<NG * 16, 64, 0, stream>>>(bufA, coef, starts, pooled);
    head_kernel<<<1, 1024, 0, stream>>>(pooled, starts, Wl, bl, Wo, bo, (float*)d_out);
}